// Round 4
// baseline (174.909 us; speedup 1.0000x reference)
//
#include <hip/hip_runtime.h>

// WaveCell FDTD step, fp32, B=8, NY=NX=1024.
// y = inv*(8*h1 - (4-2b)*h2 + c^2*lap),  b = bg + rho/(1+h1^2),
// c = c_linear + 0.01*rho*h1^2, inv = 1/(4+2b), lap = 5pt zero-pad stencil.
// Outputs concatenated: [y (8M floats), h1 copy (8M floats)].
//
// R4: attack MLP/latency. RROWS=4 (LDS 24 KB, 2048 blocks -> smoother drain),
// launch_bounds(256,5) (~20 waves/CU). All 12 stream f4 loads + 4 bg loads
// issued BEFORE the barrier (independent of LDS stage) -> ~18 outstanding
// f4 loads per wave through the stage+barrier window instead of 4.

typedef float f4 __attribute__((ext_vector_type(4)));

#define NX4   256      // float4 per row
#define NYDIM 1024
#define RROWS 4        // center rows per block

__device__ __forceinline__ float wave_pt(float h1x, float h2x, float clx,
                                         float rx, float bgx, float lap) {
    float s   = h1x * h1x;
    float b   = bgx + rx * __builtin_amdgcn_rcpf(1.0f + s);
    float c   = clx + 0.01f * rx * s;
    float inv = __builtin_amdgcn_rcpf(4.0f + 2.0f * b);
    return inv * (8.0f * h1x - (4.0f - 2.0f * b) * h2x + c * c * lap);
}

__global__ __launch_bounds__(256, 5) void wavecell_kernel(
    const f4* __restrict__ h1,
    const f4* __restrict__ h2,
    const f4* __restrict__ cl,
    const f4* __restrict__ rho,
    const f4* __restrict__ bg,
    f4*       __restrict__ out,
    int n4)   // total float4 groups = B*NY*NX/4 = 2,097,152
{
    const int tid = threadIdx.x;          // f4-column 0..255
    // XCD swizzle: hw round-robins block b -> XCD (b % 8). Map so each XCD
    // owns 32 consecutive row-groups x 8 batches: bg slice 512 KB (8x reuse),
    // vertical halo neighbors co-resident in one XCD's L2.
    const int bi  = blockIdx.x;           // 0..2047
    const int xcd = bi & 7;
    const int j   = bi >> 3;              // 0..255
    const int rg  = (xcd << 5) | (j & 31);   // row-group 0..255
    const int bat = j >> 5;                  // batch 0..7
    const int r0  = rg << 2;                 // first center row
    const int planeBase = bat << 18;         // bat * NYDIM * NX4

    __shared__ f4 lds[RROWS + 2][NX4];

    // ---- Phase 0: issue ALL independent stream loads first (deep MLP) ----
    f4 h2c[RROWS], clc[RROWS], rc[RROWS], bgc[RROWS];
    #pragma unroll
    for (int i = 0; i < RROWS; ++i) {
        const int g = planeBase + ((r0 + i) << 8) + tid;
        h2c[i] = __builtin_nontemporal_load(h2 + g);
        clc[i] = __builtin_nontemporal_load(cl + g);
        rc[i]  = __builtin_nontemporal_load(rho + g);
        bgc[i] = bg[((r0 + i) << 8) + tid];   // L2-resident slice, keep cached
    }

    // ---- Stage RROWS+2 h1 rows into LDS (zero-fill outside image) ----
    #pragma unroll
    for (int k = 0; k < RROWS + 2; ++k) {
        int gy = r0 - 1 + k;
        f4 v = {0.f, 0.f, 0.f, 0.f};
        if (gy >= 0 && gy < NYDIM) v = h1[planeBase + (gy << 8) + tid];
        lds[k][tid] = v;
    }
    __syncthreads();

    const int xl = (tid > 0)       ? tid - 1 : 0;
    const int xr = (tid < NX4 - 1) ? tid + 1 : NX4 - 1;
    const bool hasL = (tid > 0), hasR = (tid < NX4 - 1);

    #pragma unroll
    for (int i = 0; i < RROWS; ++i) {
        const int g = planeBase + ((r0 + i) << 8) + tid;

        f4 c   = lds[i + 1][tid];
        f4 t   = lds[i][tid];
        f4 bo  = lds[i + 2][tid];
        f4 lg  = lds[i + 1][xl];
        f4 rgp = lds[i + 1][xr];
        float L = hasL ? lg.w  : 0.0f;
        float R = hasR ? rgp.x : 0.0f;

        float lapx = t.x + bo.x + L   + c.y - 4.0f * c.x;
        float lapy = t.y + bo.y + c.x + c.z - 4.0f * c.y;
        float lapz = t.z + bo.z + c.y + c.w - 4.0f * c.z;
        float lapw = t.w + bo.w + c.z + R   - 4.0f * c.w;

        f4 yv;
        yv.x = wave_pt(c.x, h2c[i].x, clc[i].x, rc[i].x, bgc[i].x, lapx);
        yv.y = wave_pt(c.y, h2c[i].y, clc[i].y, rc[i].y, bgc[i].y, lapy);
        yv.z = wave_pt(c.z, h2c[i].z, clc[i].z, rc[i].z, bgc[i].z, lapz);
        yv.w = wave_pt(c.w, h2c[i].w, clc[i].w, rc[i].w, bgc[i].w, lapw);

        __builtin_nontemporal_store(yv, out + g);        // output 0: y
        __builtin_nontemporal_store(c,  out + n4 + g);   // output 1: h1
    }
}

extern "C" void kernel_launch(void* const* d_in, const int* in_sizes, int n_in,
                              void* d_out, int out_size, void* d_ws, size_t ws_size,
                              hipStream_t stream) {
    const f4* h1  = (const f4*)d_in[0];
    const f4* h2  = (const f4*)d_in[1];
    const f4* cl  = (const f4*)d_in[2];
    const f4* rho = (const f4*)d_in[3];
    const f4* bg  = (const f4*)d_in[4];
    f4* out = (f4*)d_out;

    int n  = in_sizes[0];          // 8*1024*1024
    int n4 = n / 4;                // 2,097,152 float4 groups
    // grid: 8 batches x 256 row-groups = 2048 blocks
    wavecell_kernel<<<2048, 256, 0, stream>>>(h1, h2, cl, rho, bg, out, n4);
}